// Round 10
// baseline (175.529 us; speedup 1.0000x reference)
//
#include <hip/hip_runtime.h>
#include <math.h>

#define T_ 10
#define D_ 8
#define B_ 32768
#define NSAMP (T_ * B_)   // 327680

#define DEV static __device__ __forceinline__

// ---------------------------------------------------------------------------
// Precompute (wave-uniform math):
//   WS[0..63]  : combined layer-0 gate U0_w = RZ*RY*RX per wire (8 floats/wire)
//   WS[64..95] : per wire w, B_w = Hadamard transform of A_w = U1_w† Z U1_w,
//                divided by 4: (B00, B11, BR, BI).
// ---------------------------------------------------------------------------
__global__ void precompute_U(const float* __restrict__ params, float* __restrict__ WS) {
    int idx = threadIdx.x;
    if (idx >= 16) return;
    float ax = 0.5f*params[idx*3+0], ay = 0.5f*params[idx*3+1], az = 0.5f*params[idx*3+2];
    float cx = cosf(ax), sx = sinf(ax);
    float cy = cosf(ay), sy = sinf(ay);
    float cz = cosf(az), sz = sinf(az);
    // M = RY*RX
    float m00r = cy*cx, m00i = sy*sx;
    float m01r = -sy*cx, m01i = -cy*sx;
    float m10r = sy*cx,  m10i = -cy*sx;
    float m11r = cy*cx,  m11i = -sy*sx;
    // U = RZ*M
    float u00r = cz*m00r + sz*m00i, u00i = cz*m00i - sz*m00r;
    float u01r = cz*m01r + sz*m01i, u01i = cz*m01i - sz*m01r;
    float u10r = cz*m10r - sz*m10i, u10i = cz*m10i + sz*m10r;
    float u11r = cz*m11r - sz*m11i, u11i = cz*m11i + sz*m11r;
    if (idx < 8) {
        float* o = WS + idx*8;
        o[0]=u00r; o[1]=u00i; o[2]=u01r; o[3]=u01i;
        o[4]=u10r; o[5]=u10i; o[6]=u11r; o[7]=u11i;
    } else {
        // A = u† Z u (Hermitian): α=A00, δ=A11 real; β=A01.
        float al = u00r*u00r+u00i*u00i - (u10r*u10r+u10i*u10i);
        float de = u01r*u01r+u01i*u01i - (u11r*u11r+u11i*u11i);
        float br = u00r*u01r+u00i*u01i - (u10r*u11r+u10i*u11i);
        float bi = u00r*u01i-u00i*u01r - (u10r*u11i-u10i*u11r);
        float* o = WS + 64 + (idx-8)*4;
        o[0] = 0.25f*(al+de+2.f*br);
        o[1] = 0.25f*(al+de-2.f*br);
        o[2] = 0.25f*(al-de);
        o[3] = -0.5f*bi;
    }
}

// d-vector of chain site (wire w): d = (m00, m1, conj(m1), m11) with
// m1 = mr + i*mi. Recomputed on demand (frees 28 VGPRs of arrays).
// The empty volatile asm pins placement so the compiler doesn't hoist all
// sites' sin/cos upfront (register-pressure guard).
DEV void dsite(const float* __restrict__ WS, const float* xr, int w,
               float& m00, float& m11, float& mr, float& mi) {
    float th = 0.5f * xr[w];
    asm volatile("" : "+v"(th));
    float c = __cosf(th), s = __sinf(th);
    float a0r = c*c, a0i = -c*s, a1r = c*s, a1i = s*s;
    const float* u = WS + 8*w;
    float f0r = u[0]*a0r - u[1]*a0i + u[2]*a1r - u[3]*a1i;
    float f0i = u[0]*a0i + u[1]*a0r + u[2]*a1i + u[3]*a1r;
    float f1r = u[4]*a0r - u[5]*a0i + u[6]*a1r - u[7]*a1i;
    float f1i = u[4]*a0i + u[5]*a0r + u[6]*a1i + u[7]*a1r;
    float Dpr=f0r+f1r, Dpi=f0i+f1i, Dmr=f0r-f1r, Dmi=f0i-f1i;
    m00 = Dpr*Dpr + Dpi*Dpi;
    m11 = Dmr*Dmr + Dmi*Dmi;
    mr  = Dpr*Dmr + Dpi*Dmi;
    mi  = Dpi*Dmr - Dpr*Dmi;
}

// ---------------------------------------------------------------------------
// One sample per LANE. MPS transfer-matrix contraction (R9-proven math),
// restructured for low register pressure:
//  - closure via column dots Q_m = Σ_r M[r][m] G[m^r], Q'_m (G idx ^3)
//    (algebraic rewrite of the Y-matrix closure)
//  - per-site d recomputed on demand
//  - row-wise in-place chain update
// ---------------------------------------------------------------------------
__global__ __launch_bounds__(256, 4) void sim_kernel(const float* __restrict__ X,
                                                     const float* __restrict__ WS,
                                                     float* __restrict__ qf) {
    const int n = blockIdx.x*256 + threadIdx.x;
    const float* xp = X + n*8;
    float xr[8];
    { float4 t0 = *(const float4*)xp; float4 t1 = *(const float4*)(xp+4);
      xr[0]=t0.x; xr[1]=t0.y; xr[2]=t0.z; xr[3]=t0.w;
      xr[4]=t1.x; xr[5]=t1.y; xr[6]=t1.z; xr[7]=t1.w; }

    const float B00 = WS[64], B11 = WS[65], BR0 = WS[66], BI0 = WS[67];

    // G = closure-site (wire 0) d-vector
    float G00, G11, G01r, G01i;
    dsite(WS, xr, 0, G00, G11, G01r, G01i);

    // suffix scalars: SR[wi-1] = Π_{k=wi+2..7} ρ_k, ST likewise with τ
    // (ρ = 0.5(m00+m11), τ = mr of collapsed interior I-sites).
    float SR[6], ST[6];
    SR[5]=1.f; ST[5]=1.f;
    {
        float a,b,r,i;
        dsite(WS,xr,7,a,b,r,i); SR[4]=0.5f*(a+b);       ST[4]=r;
        dsite(WS,xr,6,a,b,r,i); SR[3]=SR[4]*0.5f*(a+b); ST[3]=ST[4]*r;
        dsite(WS,xr,5,a,b,r,i); SR[2]=SR[3]*0.5f*(a+b); ST[2]=ST[3]*r;
        dsite(WS,xr,4,a,b,r,i); SR[1]=SR[2]*0.5f*(a+b); ST[1]=ST[2]*r;
        dsite(WS,xr,3,a,b,r,i); SR[0]=SR[1]*0.5f*(a+b); ST[0]=ST[1]*r;
    }

    float Mr[4][4], Mi[4][4];
    // chain init: M = diag(d_1)·circ(B_1)
    {
        float d0,d3,dr1,di1;
        dsite(WS,xr,1,d0,d3,dr1,di1);
        const float* Bp = WS + 68;
        float Bcr[4] = {Bp[0], Bp[2], Bp[2], Bp[1]};
        float Bci[4] = {0.f, -Bp[3], Bp[3], 0.f};
#pragma unroll
        for (int c = 0; c < 4; ++c) {
            Mr[0][c] = d0*Bcr[c];            Mi[0][c] = d0*Bci[c];
            Mr[1][c] = dr1*Bcr[1^c] - di1*Bci[1^c];
            Mi[1][c] = dr1*Bci[1^c] + di1*Bcr[1^c];
            Mr[2][c] = dr1*Bcr[2^c] + di1*Bci[2^c];
            Mi[2][c] = dr1*Bci[2^c] - di1*Bcr[2^c];
            Mr[3][c] = d3*Bcr[3^c];          Mi[3][c] = d3*Bci[3^c];
        }
    }

    float Ev[8];

#pragma unroll
    for (int wi = 1; wi <= 6; ++wi) {
        float d0,d3,dr1,di1;
        dsite(WS,xr,wi+1,d0,d3,dr1,di1);    // site wi+1: closure e + update
        // ---- closure: E_wi = Σ_m Re(e_m · 0.5(B0[m] Q_m + B0[m^3] Q'_m)) ----
        {
            const float Ggr[4] = {G00, G01r, G01r, G11};
            const float Ggi[4] = {0.f, G01i, -G01i, 0.f};
            float Qr[4], Qi[4], Pr_[4], Pi_[4];
#pragma unroll
            for (int m = 0; m < 4; ++m) {
                float qr=0.f,qi=0.f,pr=0.f,pi=0.f;
#pragma unroll
                for (int r = 0; r < 4; ++r) {
                    int x = m^r, x3 = x^3;
                    qr += Mr[r][m]*Ggr[x]  - Mi[r][m]*Ggi[x];
                    qi += Mr[r][m]*Ggi[x]  + Mi[r][m]*Ggr[x];
                    pr += Mr[r][m]*Ggr[x3] - Mi[r][m]*Ggi[x3];
                    pi += Mr[r][m]*Ggi[x3] + Mi[r][m]*Ggr[x3];
                }
                Qr[m]=qr; Qi[m]=qi; Pr_[m]=pr; Pi_[m]=pi;
            }
            float S0r = 0.5f*(B00*Qr[0] + B11*Pr_[0]);
            float S3r = 0.5f*(B11*Qr[3] + B00*Pr_[3]);
            float S1r = 0.5f*(BR0*Qr[1] + BI0*Qi[1] + BR0*Pr_[1] - BI0*Pi_[1]);
            float S1i = 0.5f*(BR0*Qi[1] - BI0*Qr[1] + BR0*Pi_[1] + BI0*Pr_[1]);
            float S2r = 0.5f*(BR0*Qr[2] - BI0*Qi[2] + BR0*Pr_[2] + BI0*Pi_[2]);
            float S2i = 0.5f*(BR0*Qi[2] + BI0*Qr[2] + BR0*Pi_[2] - BI0*Pr_[2]);
            float eR = SR[wi-1], eT = ST[wi-1];
            float e1r = dr1*eT, e1i = di1*eT;
            Ev[wi] = d0*eR*S0r + d3*eR*S3r
                   + e1r*S1r - e1i*S1i + e1r*S2r + e1i*S2i;
        }
        // ---- chain update: M ← M · diag(d_{wi+1}) · circ(B_{wi+1}) ----
        {
            const float* Bp = WS + 64 + 4*(wi+1);
            float Bcr[4] = {Bp[0], Bp[2], Bp[2], Bp[1]};
            float Bci[4] = {0.f, -Bp[3], Bp[3], 0.f};
#pragma unroll
            for (int r = 0; r < 4; ++r) {
                float N0r = Mr[r][0]*d0,               N0i = Mi[r][0]*d0;
                float N1r = Mr[r][1]*dr1 - Mi[r][1]*di1, N1i = Mr[r][1]*di1 + Mi[r][1]*dr1;
                float N2r = Mr[r][2]*dr1 + Mi[r][2]*di1, N2i = Mi[r][2]*dr1 - Mr[r][2]*di1;
                float N3r = Mr[r][3]*d3,               N3i = Mi[r][3]*d3;
#pragma unroll
                for (int c = 0; c < 4; ++c) {
                    float br0=Bcr[c],   bi0=Bci[c];
                    float br1=Bcr[1^c], bi1=Bci[1^c];
                    float br2=Bcr[2^c], bi2=Bci[2^c];
                    float br3=Bcr[3^c], bi3=Bci[3^c];
                    Mr[r][c] = N0r*br0 - N0i*bi0 + N1r*br1 - N1i*bi1
                             + N2r*br2 - N2i*bi2 + N3r*br3 - N3i*bi3;
                    Mi[r][c] = N0r*bi0 + N0i*br0 + N1r*bi1 + N1i*br1
                             + N2r*bi2 + N2i*br2 + N3r*bi3 + N3i*br3;
                }
            }
        }
    }

    // ---- wi = 7: E_7 = Re Σ_m B0[m] Q_m ; E_0 = 0.5 Re(Q_0 + Q_3) ----
    {
        const float Ggr[4] = {G00, G01r, G01r, G11};
        const float Ggi[4] = {0.f, G01i, -G01i, 0.f};
        float Qr[4], Qi[4];
#pragma unroll
        for (int m = 0; m < 4; ++m) {
            float qr=0.f, qi=0.f;
#pragma unroll
            for (int r = 0; r < 4; ++r) {
                int x = m^r;
                qr += Mr[r][m]*Ggr[x] - Mi[r][m]*Ggi[x];
                qi += Mr[r][m]*Ggi[x] + Mi[r][m]*Ggr[x];
            }
            Qr[m]=qr; Qi[m]=qi;
        }
        Ev[7] = B00*Qr[0] + BR0*Qr[1] + BI0*Qi[1]
              + BR0*Qr[2] - BI0*Qi[2] + B11*Qr[3];
        Ev[0] = 0.5f*(Qr[0] + Qr[3]);
    }

    const int t_ = n >> 15;          // n / B
    const int b_ = n & (B_-1);       // n % B
    float* o = qf + b_*(T_*D_) + t_*D_;
    float4 o0 = {Ev[0], Ev[1], Ev[2], Ev[3]};
    float4 o1 = {Ev[4], Ev[5], Ev[6], Ev[7]};
    *(float4*)o = o0;
    *(float4*)(o+4) = o1;
}

// One wave64 per batch row: h = qf_row @ W1 + b1 ; LayerNorm ; ReLU ; sigmoid(h @ W2 + b2)
__global__ __launch_bounds__(256) void head_kernel(const float* __restrict__ qf,
                                                   const float* __restrict__ W1,
                                                   const float* __restrict__ b1v,
                                                   const float* __restrict__ gam,
                                                   const float* __restrict__ bet,
                                                   const float* __restrict__ W2,
                                                   const float* __restrict__ b2v,
                                                   float* __restrict__ score) {
    const int lane = threadIdx.x & 63;
    int b = (blockIdx.x << 2) + (threadIdx.x >> 6);
    b = __builtin_amdgcn_readfirstlane(b);
    const float* row = qf + b * (T_ * D_);
    float h = b1v[lane];
#pragma unroll
    for (int k = 0; k < T_ * D_; ++k)
        h = fmaf(row[k], W1[(k << 6) + lane], h);
    float t = h;
#pragma unroll
    for (int m = 1; m < 64; m <<= 1) t += __shfl_xor(t, m, 64);
    float mu = t * (1.0f / 64.0f);
    float d = h - mu;
    float vv = d * d;
#pragma unroll
    for (int m = 1; m < 64; m <<= 1) vv += __shfl_xor(vv, m, 64);
    float rs = rsqrtf(vv * (1.0f / 64.0f) + 1e-5f);
    float hn = fmaxf(d * rs * gam[lane] + bet[lane], 0.f);
    float sacc = hn * W2[lane];
#pragma unroll
    for (int m = 1; m < 64; m <<= 1) sacc += __shfl_xor(sacc, m, 64);
    if (lane == 0) score[b] = 1.0f / (1.0f + expf(-(sacc + b2v[0])));
}

extern "C" void kernel_launch(void* const* d_in, const int* in_sizes, int n_in,
                              void* d_out, int out_size, void* d_ws, size_t ws_size,
                              hipStream_t stream) {
    const float* X_seq  = (const float*)d_in[0];
    const float* params = (const float*)d_in[1];
    const float* W1     = (const float*)d_in[2];
    const float* b1v    = (const float*)d_in[3];
    const float* gam    = (const float*)d_in[4];
    const float* bet    = (const float*)d_in[5];
    const float* W2     = (const float*)d_in[6];
    const float* b2v    = (const float*)d_in[7];

    float* out   = (float*)d_out;
    float* score = out;          // B floats
    float* qf    = out + B_;     // B*T*D floats
    float* WS    = (float*)d_ws; // 96 floats

    hipLaunchKernelGGL(precompute_U, dim3(1), dim3(64), 0, stream, params, WS);
    hipLaunchKernelGGL(sim_kernel, dim3(NSAMP / 256), dim3(256), 0, stream, X_seq, WS, qf);
    hipLaunchKernelGGL(head_kernel, dim3(B_ / 4), dim3(256), 0, stream,
                       qf, W1, b1v, gam, bet, W2, b2v, score);
}

// Round 11
// 173.586 us; speedup vs baseline: 1.0112x; 1.0112x over previous
//
#include <hip/hip_runtime.h>
#include <math.h>

#define T_ 10
#define D_ 8
#define B_ 32768
#define NSAMP (T_ * B_)   // 327680

#define DEV static __device__ __forceinline__

// ---------------------------------------------------------------------------
// Precompute (wave-uniform math):
//   WS[0..63]  : combined layer-0 gate U0_w = RZ*RY*RX per wire (8 floats/wire)
//   WS[64..95] : per wire w, B_w = Hadamard transform of A_w = U1_w† Z U1_w,
//                divided by 4: (B00, B11, BR, BI).
// ---------------------------------------------------------------------------
__global__ void precompute_U(const float* __restrict__ params, float* __restrict__ WS) {
    int idx = threadIdx.x;
    if (idx >= 16) return;
    float ax = 0.5f*params[idx*3+0], ay = 0.5f*params[idx*3+1], az = 0.5f*params[idx*3+2];
    float cx = cosf(ax), sx = sinf(ax);
    float cy = cosf(ay), sy = sinf(ay);
    float cz = cosf(az), sz = sinf(az);
    // M = RY*RX
    float m00r = cy*cx, m00i = sy*sx;
    float m01r = -sy*cx, m01i = -cy*sx;
    float m10r = sy*cx,  m10i = -cy*sx;
    float m11r = cy*cx,  m11i = -sy*sx;
    // U = RZ*M
    float u00r = cz*m00r + sz*m00i, u00i = cz*m00i - sz*m00r;
    float u01r = cz*m01r + sz*m01i, u01i = cz*m01i - sz*m01r;
    float u10r = cz*m10r - sz*m10i, u10i = cz*m10i + sz*m10r;
    float u11r = cz*m11r - sz*m11i, u11i = cz*m11i + sz*m11r;
    if (idx < 8) {
        float* o = WS + idx*8;
        o[0]=u00r; o[1]=u00i; o[2]=u01r; o[3]=u01i;
        o[4]=u10r; o[5]=u10i; o[6]=u11r; o[7]=u11i;
    } else {
        // A = u† Z u (Hermitian): α=A00, δ=A11 real; β=A01.
        float al = u00r*u00r+u00i*u00i - (u10r*u10r+u10i*u10i);
        float de = u01r*u01r+u01i*u01i - (u11r*u11r+u11i*u11i);
        float br = u00r*u01r+u00i*u01i - (u10r*u11r+u10i*u11i);
        float bi = u00r*u01i-u00i*u01r - (u10r*u11i-u10i*u11r);
        float* o = WS + 64 + (idx-8)*4;
        o[0] = 0.25f*(al+de+2.f*br);
        o[1] = 0.25f*(al+de-2.f*br);
        o[2] = 0.25f*(al-de);
        o[3] = -0.5f*bi;
    }
}

// d-vector of chain site: d = (m00, m1, conj(m1), m11), m1 = mr + i*mi.
// Takes th BY VALUE and pre-offset u pointer — no local-array address is
// taken (R10's `const float* xr` parameter put xr[] in scratch: 211 MB
// FETCH / 417 MB WRITE per dispatch. Scalar args keep everything in VGPRs.)
DEV void dsite(const float* __restrict__ u, float th,
               float& m00, float& m11, float& mr, float& mi) {
    asm volatile("" : "+v"(th));   // pin: don't hoist all sites' sin/cos together
    float c = __cosf(th), s = __sinf(th);
    float a0r = c*c, a0i = -c*s, a1r = c*s, a1i = s*s;
    float f0r = u[0]*a0r - u[1]*a0i + u[2]*a1r - u[3]*a1i;
    float f0i = u[0]*a0i + u[1]*a0r + u[2]*a1i + u[3]*a1r;
    float f1r = u[4]*a0r - u[5]*a0i + u[6]*a1r - u[7]*a1i;
    float f1i = u[4]*a0i + u[5]*a0r + u[6]*a1i + u[7]*a1r;
    float Dpr=f0r+f1r, Dpi=f0i+f1i, Dmr=f0r-f1r, Dmi=f0i-f1i;
    m00 = Dpr*Dpr + Dpi*Dpi;
    m11 = Dmr*Dmr + Dmi*Dmi;
    mr  = Dpr*Dmr + Dpi*Dmi;
    mi  = Dpi*Dmr - Dpr*Dmi;
}

// ---------------------------------------------------------------------------
// One sample per LANE. MPS transfer-matrix contraction (R9-proven math),
// low-register structure (R10 algebra, fixed calling convention):
//  - closure via column dots Q_m = Σ_r M[r][m] G[m^r], Q'_m (G idx ^3)
//  - per-site d recomputed on demand (scalar-arg dsite)
//  - row-wise in-place chain update
// ---------------------------------------------------------------------------
__global__ __launch_bounds__(256, 4) void sim_kernel(const float* __restrict__ X,
                                                     const float* __restrict__ WS,
                                                     float* __restrict__ qf) {
    const int n = blockIdx.x*256 + threadIdx.x;
    const float* xp = X + n*8;
    float xr[8];
    { float4 t0 = *(const float4*)xp; float4 t1 = *(const float4*)(xp+4);
      xr[0]=0.5f*t0.x; xr[1]=0.5f*t0.y; xr[2]=0.5f*t0.z; xr[3]=0.5f*t0.w;
      xr[4]=0.5f*t1.x; xr[5]=0.5f*t1.y; xr[6]=0.5f*t1.z; xr[7]=0.5f*t1.w; }

    const float B00 = WS[64], B11 = WS[65], BR0 = WS[66], BI0 = WS[67];

    // G = closure-site (wire 0) d-vector
    float G00, G11, G01r, G01i;
    dsite(WS, xr[0], G00, G11, G01r, G01i);

    // suffix scalars: SR[wi-1] = Π_{k=wi+2..7} ρ_k, ST likewise with τ
    float SR[6], ST[6];
    SR[5]=1.f; ST[5]=1.f;
    {
        float a,b,r,i;
        dsite(WS+56, xr[7], a,b,r,i); SR[4]=0.5f*(a+b);       ST[4]=r;
        dsite(WS+48, xr[6], a,b,r,i); SR[3]=SR[4]*0.5f*(a+b); ST[3]=ST[4]*r;
        dsite(WS+40, xr[5], a,b,r,i); SR[2]=SR[3]*0.5f*(a+b); ST[2]=ST[3]*r;
        dsite(WS+32, xr[4], a,b,r,i); SR[1]=SR[2]*0.5f*(a+b); ST[1]=ST[2]*r;
        dsite(WS+24, xr[3], a,b,r,i); SR[0]=SR[1]*0.5f*(a+b); ST[0]=ST[1]*r;
    }

    float Mr[4][4], Mi[4][4];
    // chain init: M = diag(d_1)·circ(B_1)
    {
        float d0,d3,dr1,di1;
        dsite(WS+8, xr[1], d0,d3,dr1,di1);
        const float* Bp = WS + 68;
        float Bcr[4] = {Bp[0], Bp[2], Bp[2], Bp[1]};
        float Bci[4] = {0.f, -Bp[3], Bp[3], 0.f};
#pragma unroll
        for (int c = 0; c < 4; ++c) {
            Mr[0][c] = d0*Bcr[c];            Mi[0][c] = d0*Bci[c];
            Mr[1][c] = dr1*Bcr[1^c] - di1*Bci[1^c];
            Mi[1][c] = dr1*Bci[1^c] + di1*Bcr[1^c];
            Mr[2][c] = dr1*Bcr[2^c] + di1*Bci[2^c];
            Mi[2][c] = dr1*Bci[2^c] - di1*Bcr[2^c];
            Mr[3][c] = d3*Bcr[3^c];          Mi[3][c] = d3*Bci[3^c];
        }
    }

    float Ev[8];

#pragma unroll
    for (int wi = 1; wi <= 6; ++wi) {
        float d0,d3,dr1,di1;
        dsite(WS + 8*(wi+1), xr[wi+1], d0,d3,dr1,di1);  // constant idx after unroll
        // ---- closure: E_wi = Σ_m Re(e_m · 0.5(B0[m] Q_m + B0[m^3] Q'_m)) ----
        {
            const float Ggr[4] = {G00, G01r, G01r, G11};
            const float Ggi[4] = {0.f, G01i, -G01i, 0.f};
            float Qr[4], Qi[4], Pr_[4], Pi_[4];
#pragma unroll
            for (int m = 0; m < 4; ++m) {
                float qr=0.f,qi=0.f,pr=0.f,pi=0.f;
#pragma unroll
                for (int r = 0; r < 4; ++r) {
                    int x = m^r, x3 = x^3;
                    qr += Mr[r][m]*Ggr[x]  - Mi[r][m]*Ggi[x];
                    qi += Mr[r][m]*Ggi[x]  + Mi[r][m]*Ggr[x];
                    pr += Mr[r][m]*Ggr[x3] - Mi[r][m]*Ggi[x3];
                    pi += Mr[r][m]*Ggi[x3] + Mi[r][m]*Ggr[x3];
                }
                Qr[m]=qr; Qi[m]=qi; Pr_[m]=pr; Pi_[m]=pi;
            }
            float S0r = 0.5f*(B00*Qr[0] + B11*Pr_[0]);
            float S3r = 0.5f*(B11*Qr[3] + B00*Pr_[3]);
            float S1r = 0.5f*(BR0*Qr[1] + BI0*Qi[1] + BR0*Pr_[1] - BI0*Pi_[1]);
            float S1i = 0.5f*(BR0*Qi[1] - BI0*Qr[1] + BR0*Pi_[1] + BI0*Pr_[1]);
            float S2r = 0.5f*(BR0*Qr[2] - BI0*Qi[2] + BR0*Pr_[2] + BI0*Pi_[2]);
            float S2i = 0.5f*(BR0*Qi[2] + BI0*Qr[2] + BR0*Pi_[2] - BI0*Pr_[2]);
            float eR = SR[wi-1], eT = ST[wi-1];
            float e1r = dr1*eT, e1i = di1*eT;
            Ev[wi] = d0*eR*S0r + d3*eR*S3r
                   + e1r*S1r - e1i*S1i + e1r*S2r + e1i*S2i;
        }
        // ---- chain update: M ← M · diag(d_{wi+1}) · circ(B_{wi+1}) ----
        {
            const float* Bp = WS + 64 + 4*(wi+1);
            float Bcr[4] = {Bp[0], Bp[2], Bp[2], Bp[1]};
            float Bci[4] = {0.f, -Bp[3], Bp[3], 0.f};
#pragma unroll
            for (int r = 0; r < 4; ++r) {
                float N0r = Mr[r][0]*d0,                 N0i = Mi[r][0]*d0;
                float N1r = Mr[r][1]*dr1 - Mi[r][1]*di1, N1i = Mr[r][1]*di1 + Mi[r][1]*dr1;
                float N2r = Mr[r][2]*dr1 + Mi[r][2]*di1, N2i = Mi[r][2]*dr1 - Mr[r][2]*di1;
                float N3r = Mr[r][3]*d3,                 N3i = Mi[r][3]*d3;
#pragma unroll
                for (int c = 0; c < 4; ++c) {
                    float br0=Bcr[c],   bi0=Bci[c];
                    float br1=Bcr[1^c], bi1=Bci[1^c];
                    float br2=Bcr[2^c], bi2=Bci[2^c];
                    float br3=Bcr[3^c], bi3=Bci[3^c];
                    Mr[r][c] = N0r*br0 - N0i*bi0 + N1r*br1 - N1i*bi1
                             + N2r*br2 - N2i*bi2 + N3r*br3 - N3i*bi3;
                    Mi[r][c] = N0r*bi0 + N0i*br0 + N1r*bi1 + N1i*br1
                             + N2r*bi2 + N2i*br2 + N3r*bi3 + N3i*br3;
                }
            }
        }
    }

    // ---- wi = 7: E_7 = Re Σ_m B0[m] Q_m ; E_0 = 0.5 Re(Q_0 + Q_3) ----
    {
        const float Ggr[4] = {G00, G01r, G01r, G11};
        const float Ggi[4] = {0.f, G01i, -G01i, 0.f};
        float Qr[4], Qi[4];
#pragma unroll
        for (int m = 0; m < 4; ++m) {
            float qr=0.f, qi=0.f;
#pragma unroll
            for (int r = 0; r < 4; ++r) {
                int x = m^r;
                qr += Mr[r][m]*Ggr[x] - Mi[r][m]*Ggi[x];
                qi += Mr[r][m]*Ggi[x] + Mi[r][m]*Ggr[x];
            }
            Qr[m]=qr; Qi[m]=qi;
        }
        Ev[7] = B00*Qr[0] + BR0*Qr[1] + BI0*Qi[1]
              + BR0*Qr[2] - BI0*Qi[2] + B11*Qr[3];
        Ev[0] = 0.5f*(Qr[0] + Qr[3]);
    }

    const int t_ = n >> 15;          // n / B
    const int b_ = n & (B_-1);       // n % B
    float* o = qf + b_*(T_*D_) + t_*D_;
    float4 o0 = {Ev[0], Ev[1], Ev[2], Ev[3]};
    float4 o1 = {Ev[4], Ev[5], Ev[6], Ev[7]};
    *(float4*)o = o0;
    *(float4*)(o+4) = o1;
}

// One wave64 per batch row: h = qf_row @ W1 + b1 ; LayerNorm ; ReLU ; sigmoid(h @ W2 + b2)
__global__ __launch_bounds__(256) void head_kernel(const float* __restrict__ qf,
                                                   const float* __restrict__ W1,
                                                   const float* __restrict__ b1v,
                                                   const float* __restrict__ gam,
                                                   const float* __restrict__ bet,
                                                   const float* __restrict__ W2,
                                                   const float* __restrict__ b2v,
                                                   float* __restrict__ score) {
    const int lane = threadIdx.x & 63;
    int b = (blockIdx.x << 2) + (threadIdx.x >> 6);
    b = __builtin_amdgcn_readfirstlane(b);
    const float* row = qf + b * (T_ * D_);
    float h = b1v[lane];
#pragma unroll
    for (int k = 0; k < T_ * D_; ++k)
        h = fmaf(row[k], W1[(k << 6) + lane], h);
    float t = h;
#pragma unroll
    for (int m = 1; m < 64; m <<= 1) t += __shfl_xor(t, m, 64);
    float mu = t * (1.0f / 64.0f);
    float d = h - mu;
    float vv = d * d;
#pragma unroll
    for (int m = 1; m < 64; m <<= 1) vv += __shfl_xor(vv, m, 64);
    float rs = rsqrtf(vv * (1.0f / 64.0f) + 1e-5f);
    float hn = fmaxf(d * rs * gam[lane] + bet[lane], 0.f);
    float sacc = hn * W2[lane];
#pragma unroll
    for (int m = 1; m < 64; m <<= 1) sacc += __shfl_xor(sacc, m, 64);
    if (lane == 0) score[b] = 1.0f / (1.0f + expf(-(sacc + b2v[0])));
}

extern "C" void kernel_launch(void* const* d_in, const int* in_sizes, int n_in,
                              void* d_out, int out_size, void* d_ws, size_t ws_size,
                              hipStream_t stream) {
    const float* X_seq  = (const float*)d_in[0];
    const float* params = (const float*)d_in[1];
    const float* W1     = (const float*)d_in[2];
    const float* b1v    = (const float*)d_in[3];
    const float* gam    = (const float*)d_in[4];
    const float* bet    = (const float*)d_in[5];
    const float* W2     = (const float*)d_in[6];
    const float* b2v    = (const float*)d_in[7];

    float* out   = (float*)d_out;
    float* score = out;          // B floats
    float* qf    = out + B_;     // B*T*D floats
    float* WS    = (float*)d_ws; // 96 floats

    hipLaunchKernelGGL(precompute_U, dim3(1), dim3(64), 0, stream, params, WS);
    hipLaunchKernelGGL(sim_kernel, dim3(NSAMP / 256), dim3(256), 0, stream, X_seq, WS, qf);
    hipLaunchKernelGGL(head_kernel, dim3(B_ / 4), dim3(256), 0, stream,
                       qf, W1, b1v, gam, bet, W2, b2v, score);
}

// Round 12
// 120.203 us; speedup vs baseline: 1.4603x; 1.4441x over previous
//
#include <hip/hip_runtime.h>
#include <math.h>

#define T_ 10
#define D_ 8
#define B_ 32768
#define NSAMP (T_ * B_)   // 327680

#define DEV static __device__ __forceinline__

// ---------------------------------------------------------------------------
// Precompute (wave-uniform math):
//   WS[0..63]  : combined layer-0 gate U0_w = RZ*RY*RX per wire (8 floats/wire)
//   WS[64..95] : per wire w, B_w = Hadamard transform of A_w = U1_w† Z U1_w,
//                divided by 4: (B00, B11, BR, BI).
// ---------------------------------------------------------------------------
__global__ void precompute_U(const float* __restrict__ params, float* __restrict__ WS) {
    int idx = threadIdx.x;
    if (idx >= 16) return;
    float ax = 0.5f*params[idx*3+0], ay = 0.5f*params[idx*3+1], az = 0.5f*params[idx*3+2];
    float cx = cosf(ax), sx = sinf(ax);
    float cy = cosf(ay), sy = sinf(ay);
    float cz = cosf(az), sz = sinf(az);
    // M = RY*RX
    float m00r = cy*cx, m00i = sy*sx;
    float m01r = -sy*cx, m01i = -cy*sx;
    float m10r = sy*cx,  m10i = -cy*sx;
    float m11r = cy*cx,  m11i = -sy*sx;
    // U = RZ*M
    float u00r = cz*m00r + sz*m00i, u00i = cz*m00i - sz*m00r;
    float u01r = cz*m01r + sz*m01i, u01i = cz*m01i - sz*m01r;
    float u10r = cz*m10r - sz*m10i, u10i = cz*m10i + sz*m10r;
    float u11r = cz*m11r - sz*m11i, u11i = cz*m11i + sz*m11r;
    if (idx < 8) {
        float* o = WS + idx*8;
        o[0]=u00r; o[1]=u00i; o[2]=u01r; o[3]=u01i;
        o[4]=u10r; o[5]=u10i; o[6]=u11r; o[7]=u11i;
    } else {
        // A = u† Z u (Hermitian): α=A00, δ=A11 real; β=A01.
        float al = u00r*u00r+u00i*u00i - (u10r*u10r+u10i*u10i);
        float de = u01r*u01r+u01i*u01i - (u11r*u11r+u11i*u11i);
        float br = u00r*u01r+u00i*u01i - (u10r*u11r+u10i*u11i);
        float bi = u00r*u01i-u00i*u01r - (u10r*u11i-u10i*u11r);
        float* o = WS + 64 + (idx-8)*4;
        o[0] = 0.25f*(al+de+2.f*br);
        o[1] = 0.25f*(al+de-2.f*br);
        o[2] = 0.25f*(al-de);
        o[3] = -0.5f*bi;
    }
}

// d-vector of chain site: d = (m00, m1, conj(m1), m11), m1 = mr + i*mi.
DEV void dsite(const float* __restrict__ u, float th,
               float& m00, float& m11, float& mr, float& mi) {
    asm volatile("" : "+v"(th));   // pin: don't hoist all sites' sin/cos together
    float c = __cosf(th), s = __sinf(th);
    float a0r = c*c, a0i = -c*s, a1r = c*s, a1i = s*s;
    float f0r = u[0]*a0r - u[1]*a0i + u[2]*a1r - u[3]*a1i;
    float f0i = u[0]*a0i + u[1]*a0r + u[2]*a1i + u[3]*a1r;
    float f1r = u[4]*a0r - u[5]*a0i + u[6]*a1r - u[7]*a1i;
    float f1i = u[4]*a0i + u[5]*a0r + u[6]*a1i + u[7]*a1r;
    float Dpr=f0r+f1r, Dpi=f0i+f1i, Dmr=f0r-f1r, Dmi=f0i-f1i;
    m00 = Dpr*Dpr + Dpi*Dpi;
    m11 = Dmr*Dmr + Dmi*Dmi;
    mr  = Dpr*Dmr + Dpi*Dmi;
    mi  = Dpi*Dmr - Dpr*Dmi;
}

// ---------------------------------------------------------------------------
// One sample per LANE. MPS transfer-matrix contraction (R9-proven math),
// low-register structure (R10/R11 algebra).
// Launch bounds (256, 3): VGPR cap ~170 — fits the ~150-reg natural demand
// with NO spill at 3 waves/SIMD. (256,4)'s 128-cap caused 300 floats/lane of
// scratch spill (R10/R11: 211 MB FETCH / 417 MB WRITE, 156 µs).
// ---------------------------------------------------------------------------
__global__ __launch_bounds__(256, 3) void sim_kernel(const float* __restrict__ X,
                                                     const float* __restrict__ WS,
                                                     float* __restrict__ qf) {
    const int n = blockIdx.x*256 + threadIdx.x;
    const float* xp = X + n*8;
    float xr[8];
    { float4 t0 = *(const float4*)xp; float4 t1 = *(const float4*)(xp+4);
      xr[0]=0.5f*t0.x; xr[1]=0.5f*t0.y; xr[2]=0.5f*t0.z; xr[3]=0.5f*t0.w;
      xr[4]=0.5f*t1.x; xr[5]=0.5f*t1.y; xr[6]=0.5f*t1.z; xr[7]=0.5f*t1.w; }

    const float B00 = WS[64], B11 = WS[65], BR0 = WS[66], BI0 = WS[67];

    // G = closure-site (wire 0) d-vector
    float G00, G11, G01r, G01i;
    dsite(WS, xr[0], G00, G11, G01r, G01i);

    // suffix scalars: SR[wi-1] = Π_{k=wi+2..7} ρ_k, ST likewise with τ
    float SR[6], ST[6];
    SR[5]=1.f; ST[5]=1.f;
    {
        float a,b,r,i;
        dsite(WS+56, xr[7], a,b,r,i); SR[4]=0.5f*(a+b);       ST[4]=r;
        dsite(WS+48, xr[6], a,b,r,i); SR[3]=SR[4]*0.5f*(a+b); ST[3]=ST[4]*r;
        dsite(WS+40, xr[5], a,b,r,i); SR[2]=SR[3]*0.5f*(a+b); ST[2]=ST[3]*r;
        dsite(WS+32, xr[4], a,b,r,i); SR[1]=SR[2]*0.5f*(a+b); ST[1]=ST[2]*r;
        dsite(WS+24, xr[3], a,b,r,i); SR[0]=SR[1]*0.5f*(a+b); ST[0]=ST[1]*r;
    }

    float Mr[4][4], Mi[4][4];
    // chain init: M = diag(d_1)·circ(B_1)
    {
        float d0,d3,dr1,di1;
        dsite(WS+8, xr[1], d0,d3,dr1,di1);
        const float* Bp = WS + 68;
        float Bcr[4] = {Bp[0], Bp[2], Bp[2], Bp[1]};
        float Bci[4] = {0.f, -Bp[3], Bp[3], 0.f};
#pragma unroll
        for (int c = 0; c < 4; ++c) {
            Mr[0][c] = d0*Bcr[c];            Mi[0][c] = d0*Bci[c];
            Mr[1][c] = dr1*Bcr[1^c] - di1*Bci[1^c];
            Mi[1][c] = dr1*Bci[1^c] + di1*Bcr[1^c];
            Mr[2][c] = dr1*Bcr[2^c] + di1*Bci[2^c];
            Mi[2][c] = dr1*Bci[2^c] - di1*Bcr[2^c];
            Mr[3][c] = d3*Bcr[3^c];          Mi[3][c] = d3*Bci[3^c];
        }
    }

    float Ev[8];

#pragma unroll
    for (int wi = 1; wi <= 6; ++wi) {
        float d0,d3,dr1,di1;
        dsite(WS + 8*(wi+1), xr[wi+1], d0,d3,dr1,di1);  // constant idx after unroll
        // ---- closure: E_wi = Σ_m Re(e_m · 0.5(B0[m] Q_m + B0[m^3] Q'_m)) ----
        {
            const float Ggr[4] = {G00, G01r, G01r, G11};
            const float Ggi[4] = {0.f, G01i, -G01i, 0.f};
            float Qr[4], Qi[4], Pr_[4], Pi_[4];
#pragma unroll
            for (int m = 0; m < 4; ++m) {
                float qr=0.f,qi=0.f,pr=0.f,pi=0.f;
#pragma unroll
                for (int r = 0; r < 4; ++r) {
                    int x = m^r, x3 = x^3;
                    qr += Mr[r][m]*Ggr[x]  - Mi[r][m]*Ggi[x];
                    qi += Mr[r][m]*Ggi[x]  + Mi[r][m]*Ggr[x];
                    pr += Mr[r][m]*Ggr[x3] - Mi[r][m]*Ggi[x3];
                    pi += Mr[r][m]*Ggi[x3] + Mi[r][m]*Ggr[x3];
                }
                Qr[m]=qr; Qi[m]=qi; Pr_[m]=pr; Pi_[m]=pi;
            }
            float S0r = 0.5f*(B00*Qr[0] + B11*Pr_[0]);
            float S3r = 0.5f*(B11*Qr[3] + B00*Pr_[3]);
            float S1r = 0.5f*(BR0*Qr[1] + BI0*Qi[1] + BR0*Pr_[1] - BI0*Pi_[1]);
            float S1i = 0.5f*(BR0*Qi[1] - BI0*Qr[1] + BR0*Pi_[1] + BI0*Pr_[1]);
            float S2r = 0.5f*(BR0*Qr[2] - BI0*Qi[2] + BR0*Pr_[2] + BI0*Pi_[2]);
            float S2i = 0.5f*(BR0*Qi[2] + BI0*Qr[2] + BR0*Pi_[2] - BI0*Pr_[2]);
            float eR = SR[wi-1], eT = ST[wi-1];
            float e1r = dr1*eT, e1i = di1*eT;
            Ev[wi] = d0*eR*S0r + d3*eR*S3r
                   + e1r*S1r - e1i*S1i + e1r*S2r + e1i*S2i;
        }
        // ---- chain update: M ← M · diag(d_{wi+1}) · circ(B_{wi+1}) ----
        {
            const float* Bp = WS + 64 + 4*(wi+1);
            float Bcr[4] = {Bp[0], Bp[2], Bp[2], Bp[1]};
            float Bci[4] = {0.f, -Bp[3], Bp[3], 0.f};
#pragma unroll
            for (int r = 0; r < 4; ++r) {
                float N0r = Mr[r][0]*d0,                 N0i = Mi[r][0]*d0;
                float N1r = Mr[r][1]*dr1 - Mi[r][1]*di1, N1i = Mr[r][1]*di1 + Mi[r][1]*dr1;
                float N2r = Mr[r][2]*dr1 + Mi[r][2]*di1, N2i = Mi[r][2]*dr1 - Mr[r][2]*di1;
                float N3r = Mr[r][3]*d3,                 N3i = Mi[r][3]*d3;
#pragma unroll
                for (int c = 0; c < 4; ++c) {
                    float br0=Bcr[c],   bi0=Bci[c];
                    float br1=Bcr[1^c], bi1=Bci[1^c];
                    float br2=Bcr[2^c], bi2=Bci[2^c];
                    float br3=Bcr[3^c], bi3=Bci[3^c];
                    Mr[r][c] = N0r*br0 - N0i*bi0 + N1r*br1 - N1i*bi1
                             + N2r*br2 - N2i*bi2 + N3r*br3 - N3i*bi3;
                    Mi[r][c] = N0r*bi0 + N0i*br0 + N1r*bi1 + N1i*br1
                             + N2r*bi2 + N2i*br2 + N3r*bi3 + N3i*br3;
                }
            }
        }
    }

    // ---- wi = 7: E_7 = Re Σ_m B0[m] Q_m ; E_0 = 0.5 Re(Q_0 + Q_3) ----
    {
        const float Ggr[4] = {G00, G01r, G01r, G11};
        const float Ggi[4] = {0.f, G01i, -G01i, 0.f};
        float Qr[4], Qi[4];
#pragma unroll
        for (int m = 0; m < 4; ++m) {
            float qr=0.f, qi=0.f;
#pragma unroll
            for (int r = 0; r < 4; ++r) {
                int x = m^r;
                qr += Mr[r][m]*Ggr[x] - Mi[r][m]*Ggi[x];
                qi += Mr[r][m]*Ggi[x] + Mi[r][m]*Ggr[x];
            }
            Qr[m]=qr; Qi[m]=qi;
        }
        Ev[7] = B00*Qr[0] + BR0*Qr[1] + BI0*Qi[1]
              + BR0*Qr[2] - BI0*Qi[2] + B11*Qr[3];
        Ev[0] = 0.5f*(Qr[0] + Qr[3]);
    }

    const int t_ = n >> 15;          // n / B
    const int b_ = n & (B_-1);       // n % B
    float* o = qf + b_*(T_*D_) + t_*D_;
    float4 o0 = {Ev[0], Ev[1], Ev[2], Ev[3]};
    float4 o1 = {Ev[4], Ev[5], Ev[6], Ev[7]};
    *(float4*)o = o0;
    *(float4*)(o+4) = o1;
}

// One wave64 per batch row: h = qf_row @ W1 + b1 ; LayerNorm ; ReLU ; sigmoid(h @ W2 + b2)
__global__ __launch_bounds__(256) void head_kernel(const float* __restrict__ qf,
                                                   const float* __restrict__ W1,
                                                   const float* __restrict__ b1v,
                                                   const float* __restrict__ gam,
                                                   const float* __restrict__ bet,
                                                   const float* __restrict__ W2,
                                                   const float* __restrict__ b2v,
                                                   float* __restrict__ score) {
    const int lane = threadIdx.x & 63;
    int b = (blockIdx.x << 2) + (threadIdx.x >> 6);
    b = __builtin_amdgcn_readfirstlane(b);
    const float* row = qf + b * (T_ * D_);
    float h = b1v[lane];
#pragma unroll
    for (int k = 0; k < T_ * D_; ++k)
        h = fmaf(row[k], W1[(k << 6) + lane], h);
    float t = h;
#pragma unroll
    for (int m = 1; m < 64; m <<= 1) t += __shfl_xor(t, m, 64);
    float mu = t * (1.0f / 64.0f);
    float d = h - mu;
    float vv = d * d;
#pragma unroll
    for (int m = 1; m < 64; m <<= 1) vv += __shfl_xor(vv, m, 64);
    float rs = rsqrtf(vv * (1.0f / 64.0f) + 1e-5f);
    float hn = fmaxf(d * rs * gam[lane] + bet[lane], 0.f);
    float sacc = hn * W2[lane];
#pragma unroll
    for (int m = 1; m < 64; m <<= 1) sacc += __shfl_xor(sacc, m, 64);
    if (lane == 0) score[b] = 1.0f / (1.0f + expf(-(sacc + b2v[0])));
}

extern "C" void kernel_launch(void* const* d_in, const int* in_sizes, int n_in,
                              void* d_out, int out_size, void* d_ws, size_t ws_size,
                              hipStream_t stream) {
    const float* X_seq  = (const float*)d_in[0];
    const float* params = (const float*)d_in[1];
    const float* W1     = (const float*)d_in[2];
    const float* b1v    = (const float*)d_in[3];
    const float* gam    = (const float*)d_in[4];
    const float* bet    = (const float*)d_in[5];
    const float* W2     = (const float*)d_in[6];
    const float* b2v    = (const float*)d_in[7];

    float* out   = (float*)d_out;
    float* score = out;          // B floats
    float* qf    = out + B_;     // B*T*D floats
    float* WS    = (float*)d_ws; // 96 floats

    hipLaunchKernelGGL(precompute_U, dim3(1), dim3(64), 0, stream, params, WS);
    hipLaunchKernelGGL(sim_kernel, dim3(NSAMP / 256), dim3(256), 0, stream, X_seq, WS, qf);
    hipLaunchKernelGGL(head_kernel, dim3(B_ / 4), dim3(256), 0, stream,
                       qf, W1, b1v, gam, bet, W2, b2v, score);
}

// Round 13
// 80.474 us; speedup vs baseline: 2.1812x; 1.4937x over previous
//
#include <hip/hip_runtime.h>
#include <math.h>

#define T_ 10
#define D_ 8
#define B_ 32768
#define NSAMP (T_ * B_)   // 327680

#define DEV static __device__ __forceinline__

// ---------------------------------------------------------------------------
// Precompute (wave-uniform math):
//   WS[0..63]  : combined layer-0 gate U0_w = RZ*RY*RX per wire (8 floats/wire)
//   WS[64..95] : per wire w, B_w = Hadamard transform of A_w = U1_w† Z U1_w,
//                divided by 4: (B00, B11, BR, BI); B[1] = BR - i*BI.
// ---------------------------------------------------------------------------
__global__ void precompute_U(const float* __restrict__ params, float* __restrict__ WS) {
    int idx = threadIdx.x;
    if (idx >= 16) return;
    float ax = 0.5f*params[idx*3+0], ay = 0.5f*params[idx*3+1], az = 0.5f*params[idx*3+2];
    float cx = cosf(ax), sx = sinf(ax);
    float cy = cosf(ay), sy = sinf(ay);
    float cz = cosf(az), sz = sinf(az);
    // M = RY*RX
    float m00r = cy*cx, m00i = sy*sx;
    float m01r = -sy*cx, m01i = -cy*sx;
    float m10r = sy*cx,  m10i = -cy*sx;
    float m11r = cy*cx,  m11i = -sy*sx;
    // U = RZ*M
    float u00r = cz*m00r + sz*m00i, u00i = cz*m00i - sz*m00r;
    float u01r = cz*m01r + sz*m01i, u01i = cz*m01i - sz*m01r;
    float u10r = cz*m10r - sz*m10i, u10i = cz*m10i + sz*m10r;
    float u11r = cz*m11r - sz*m11i, u11i = cz*m11i + sz*m11r;
    if (idx < 8) {
        float* o = WS + idx*8;
        o[0]=u00r; o[1]=u00i; o[2]=u01r; o[3]=u01i;
        o[4]=u10r; o[5]=u10i; o[6]=u11r; o[7]=u11i;
    } else {
        // A = u† Z u (Hermitian): α=A00, δ=A11 real; β=A01.
        float al = u00r*u00r+u00i*u00i - (u10r*u10r+u10i*u10i);
        float de = u01r*u01r+u01i*u01i - (u11r*u11r+u11i*u11i);
        float br = u00r*u01r+u00i*u01i - (u10r*u11r+u10i*u11i);
        float bi = u00r*u01i-u00i*u01r - (u10r*u11i-u10i*u11r);
        float* o = WS + 64 + (idx-8)*4;
        o[0] = 0.25f*(al+de+2.f*br);
        o[1] = 0.25f*(al+de-2.f*br);
        o[2] = 0.25f*(al-de);
        o[3] = -0.5f*bi;
    }
}

// d-vector of chain site: d = (d0, m1, conj(m1), d3), m1 = mr + i*mi.
DEV void dsite(const float* __restrict__ u, float th,
               float& d0, float& d3, float& mr, float& mi) {
    asm volatile("" : "+v"(th));   // pin: don't hoist all sites' sin/cos together
    float c = __cosf(th), s = __sinf(th);
    float a0r = c*c, a0i = -c*s, a1r = c*s, a1i = s*s;
    float f0r = u[0]*a0r - u[1]*a0i + u[2]*a1r - u[3]*a1i;
    float f0i = u[0]*a0i + u[1]*a0r + u[2]*a1i + u[3]*a1r;
    float f1r = u[4]*a0r - u[5]*a0i + u[6]*a1r - u[7]*a1i;
    float f1i = u[4]*a0i + u[5]*a0r + u[6]*a1i + u[7]*a1r;
    float Dpr=f0r+f1r, Dpi=f0i+f1i, Dmr=f0r-f1r, Dmi=f0i-f1i;
    d0 = Dpr*Dpr + Dpi*Dpi;
    d3 = Dmr*Dmr + Dmi*Dmi;
    mr = Dpr*Dmr + Dpi*Dmi;
    mi = Dpi*Dmr - Dpr*Dmi;
}

// ---------------------------------------------------------------------------
// One sample per LANE. MPS transfer-matrix contraction (R9/R12-proven math)
// with the chain's involution symmetry exploited: sigma = bit-swap (1<->2),
// M[r][c] = conj(M[sigma r][sigma c]) (holds at init, preserved by updates).
// Independent state (16 reals): a0=M00,a3=M03,c0=M30,c3=M33 (real),
// a1=M01, c1=M31 (complex), b0..b3 = row 1 (complex). Row 2 never computed.
// Closure: Q0,Q3,P0,P3 real; Q2=conj(Q1), S2=conj(S1).
// No launch_bounds: natural allocation (the (256,K) caps in R10-R12 caused
// 130-270 MB of scratch spill; natural demand now ~halved).
// ---------------------------------------------------------------------------
__global__ void sim_kernel(const float* __restrict__ X,
                           const float* __restrict__ WS,
                           float* __restrict__ qf) {
    const int n = blockIdx.x*256 + threadIdx.x;
    const float* xp = X + n*8;
    float xr[8];
    { float4 t0 = *(const float4*)xp; float4 t1 = *(const float4*)(xp+4);
      xr[0]=0.5f*t0.x; xr[1]=0.5f*t0.y; xr[2]=0.5f*t0.z; xr[3]=0.5f*t0.w;
      xr[4]=0.5f*t1.x; xr[5]=0.5f*t1.y; xr[6]=0.5f*t1.z; xr[7]=0.5f*t1.w; }

    const float B00 = WS[64], B11 = WS[65], BR0 = WS[66], BI0 = WS[67];

    // G = closure-site (wire 0) d-vector; Gg1 = G01r + i*G01i
    float G00, G11, G01r, G01i;
    dsite(WS, xr[0], G00, G11, G01r, G01i);

    // suffix scalars: SR[wi-1] = prod_{k=wi+2..7} rho_k, ST with tau
    float SR[6], ST[6];
    SR[5]=1.f; ST[5]=1.f;
    {
        float a,b,r,i;
        dsite(WS+56, xr[7], a,b,r,i); SR[4]=0.5f*(a+b);       ST[4]=r;
        dsite(WS+48, xr[6], a,b,r,i); SR[3]=SR[4]*0.5f*(a+b); ST[3]=ST[4]*r;
        dsite(WS+40, xr[5], a,b,r,i); SR[2]=SR[3]*0.5f*(a+b); ST[2]=ST[3]*r;
        dsite(WS+32, xr[4], a,b,r,i); SR[1]=SR[2]*0.5f*(a+b); ST[1]=ST[2]*r;
        dsite(WS+24, xr[3], a,b,r,i); SR[0]=SR[1]*0.5f*(a+b); ST[0]=ST[1]*r;
    }

    // ---- init: M = diag(d_1)·circ(B_1), symmetric representation ----
    float a0,a3,a1r,a1i, c0,c3,c1r,c1i, b0r,b0i,b1r,b1i,b2r,b2i,b3r,b3i;
    {
        float D0,D3,Dmr,Dmi;
        dsite(WS+8, xr[1], D0,D3,Dmr,Dmi);
        const float C0n=WS[68], C3n=WS[69], CRn=WS[70], CIn=WS[71]; // B1 = CR - i*CI
        a0 = D0*C0n;  a3 = D0*C3n;  a1r = D0*CRn;  a1i = -D0*CIn;
        c0 = D3*C3n;  c3 = D3*C0n;  c1r = D3*CRn;  c1i =  D3*CIn;
        b0r = Dmr*CRn + Dmi*CIn;  b0i = Dmi*CRn - Dmr*CIn;   // m1*C[1]
        b1r = Dmr*C0n;            b1i = Dmi*C0n;             // m1*C[0]
        b2r = Dmr*C3n;            b2i = Dmi*C3n;             // m1*C[3]
        b3r = Dmr*CRn - Dmi*CIn;  b3i = Dmr*CIn + Dmi*CRn;   // m1*conj(C[1])
    }

    float Ev[8];

#pragma unroll
    for (int wi = 1; wi <= 6; ++wi) {
        float d0,d3,mr,mi;
        dsite(WS + 8*(wi+1), xr[wi+1], d0,d3,mr,mi);  // site wi+1: closure e + update

        // ---- closure: E_wi (uses M = sites 1..wi) ----
        {
            float Q0 = a0*G00 + c0*G11 + 2.f*(b0r*G01r - b0i*G01i);
            float Q3 = a3*G11 + c3*G00 + 2.f*(b3r*G01r + b3i*G01i);
            float Q1r = a1r*G01r - a1i*G01i + b1r*G00 + b2r*G11 + c1r*G01r + c1i*G01i;
            float Q1i = a1r*G01i + a1i*G01r + b1i*G00 - b2i*G11 + c1i*G01r - c1r*G01i;
            float P0 = a0*G11 + c0*G00 + 2.f*(b0r*G01r + b0i*G01i);
            float P3 = a3*G00 + c3*G11 + 2.f*(b3r*G01r - b3i*G01i);
            float P1r = a1r*G01r + a1i*G01i + b1r*G11 + b2r*G00 + c1r*G01r - c1i*G01i;
            float P1i = -a1r*G01i + a1i*G01r + b1i*G11 - b2i*G00 + c1i*G01r + c1r*G01i;
            float S0 = 0.5f*(B00*Q0 + B11*P0);
            float S3 = 0.5f*(B11*Q3 + B00*P3);
            float S1r = 0.5f*(BR0*Q1r + BI0*Q1i + BR0*P1r - BI0*P1i);
            float S1i = 0.5f*(BR0*Q1i - BI0*Q1r + BR0*P1i + BI0*P1r);
            float eR = SR[wi-1], eT = ST[wi-1];
            float e1r = mr*eT, e1i = mi*eT;
            Ev[wi] = eR*(d0*S0 + d3*S3) + 2.f*(e1r*S1r - e1i*S1i);
        }

        // ---- update: M <- M · diag(d_{wi+1}) · circ(B_{wi+1}) ----
        {
            const float* Bp = WS + 64 + 4*(wi+1);
            const float C0n=Bp[0], C3n=Bp[1], CRn=Bp[2], CIn=Bp[3]; // C1 = CR - i*CI
            // row 0
            float n0 = a0*d0, n3 = a3*d3;
            float n1r = a1r*mr - a1i*mi, n1i = a1r*mi + a1i*mr;
            a0  = n0*C0n + n3*C3n + 2.f*(n1r*CRn + n1i*CIn);
            a3  = n0*C3n + n3*C0n + 2.f*(n1r*CRn - n1i*CIn);
            a1r = (n0+n3)*CRn + n1r*(C0n+C3n);
            a1i = (n3-n0)*CIn + n1i*(C0n-C3n);
            // row 3
            float p0 = c0*d0, p3 = c3*d3;
            float p1r = c1r*mr - c1i*mi, p1i = c1r*mi + c1i*mr;
            c0  = p0*C0n + p3*C3n + 2.f*(p1r*CRn + p1i*CIn);
            c3  = p0*C3n + p3*C0n + 2.f*(p1r*CRn - p1i*CIn);
            c1r = (p0+p3)*CRn + p1r*(C0n+C3n);
            c1i = (p3-p0)*CIn + p1i*(C0n-C3n);
            // row 1
            float q0r = b0r*d0, q0i = b0i*d0;
            float q1r = b1r*mr - b1i*mi, q1i = b1r*mi + b1i*mr;
            float q2r = b2r*mr + b2i*mi, q2i = b2i*mr - b2r*mi;
            float q3r = b3r*d3, q3i = b3i*d3;
            float nb0r = q0r*C0n + q1r*CRn + q1i*CIn + q2r*CRn - q2i*CIn + q3r*C3n;
            float nb0i = q0i*C0n + q1i*CRn - q1r*CIn + q2i*CRn + q2r*CIn + q3i*C3n;
            float nb1r = q0r*CRn + q0i*CIn + q1r*C0n + q2r*C3n + q3r*CRn - q3i*CIn;
            float nb1i = q0i*CRn - q0r*CIn + q1i*C0n + q2i*C3n + q3i*CRn + q3r*CIn;
            float nb2r = q0r*CRn - q0i*CIn + q1r*C3n + q2r*C0n + q3r*CRn + q3i*CIn;
            float nb2i = q0i*CRn + q0r*CIn + q1i*C3n + q2i*C0n + q3i*CRn - q3r*CIn;
            float nb3r = q0r*C3n + q1r*CRn - q1i*CIn + q2r*CRn + q2i*CIn + q3r*C0n;
            float nb3i = q0i*C3n + q1i*CRn + q1r*CIn + q2i*CRn - q2r*CIn + q3i*C0n;
            b0r=nb0r; b0i=nb0i; b1r=nb1r; b1i=nb1i;
            b2r=nb2r; b2i=nb2i; b3r=nb3r; b3i=nb3i;
        }
    }

    // ---- final closures from M = sites 1..7 ----
    {
        float Q0 = a0*G00 + c0*G11 + 2.f*(b0r*G01r - b0i*G01i);
        float Q3 = a3*G11 + c3*G00 + 2.f*(b3r*G01r + b3i*G01i);
        float Q1r = a1r*G01r - a1i*G01i + b1r*G00 + b2r*G11 + c1r*G01r + c1i*G01i;
        float Q1i = a1r*G01i + a1i*G01r + b1i*G00 - b2i*G11 + c1i*G01r - c1r*G01i;
        Ev[7] = B00*Q0 + B11*Q3 + 2.f*(BR0*Q1r + BI0*Q1i);
        Ev[0] = 0.5f*(Q0 + Q3);
    }

    const int t_ = n >> 15;          // n / B
    const int b_ = n & (B_-1);       // n % B
    float* o = qf + b_*(T_*D_) + t_*D_;
    float4 o0 = {Ev[0], Ev[1], Ev[2], Ev[3]};
    float4 o1 = {Ev[4], Ev[5], Ev[6], Ev[7]};
    *(float4*)o = o0;
    *(float4*)(o+4) = o1;
}

// One wave64 per batch row: h = qf_row @ W1 + b1 ; LayerNorm ; ReLU ; sigmoid(h @ W2 + b2)
__global__ __launch_bounds__(256) void head_kernel(const float* __restrict__ qf,
                                                   const float* __restrict__ W1,
                                                   const float* __restrict__ b1v,
                                                   const float* __restrict__ gam,
                                                   const float* __restrict__ bet,
                                                   const float* __restrict__ W2,
                                                   const float* __restrict__ b2v,
                                                   float* __restrict__ score) {
    const int lane = threadIdx.x & 63;
    int b = (blockIdx.x << 2) + (threadIdx.x >> 6);
    b = __builtin_amdgcn_readfirstlane(b);
    const float* row = qf + b * (T_ * D_);
    float h = b1v[lane];
#pragma unroll
    for (int k = 0; k < T_ * D_; ++k)
        h = fmaf(row[k], W1[(k << 6) + lane], h);
    float t = h;
#pragma unroll
    for (int m = 1; m < 64; m <<= 1) t += __shfl_xor(t, m, 64);
    float mu = t * (1.0f / 64.0f);
    float d = h - mu;
    float vv = d * d;
#pragma unroll
    for (int m = 1; m < 64; m <<= 1) vv += __shfl_xor(vv, m, 64);
    float rs = rsqrtf(vv * (1.0f / 64.0f) + 1e-5f);
    float hn = fmaxf(d * rs * gam[lane] + bet[lane], 0.f);
    float sacc = hn * W2[lane];
#pragma unroll
    for (int m = 1; m < 64; m <<= 1) sacc += __shfl_xor(sacc, m, 64);
    if (lane == 0) score[b] = 1.0f / (1.0f + expf(-(sacc + b2v[0])));
}

extern "C" void kernel_launch(void* const* d_in, const int* in_sizes, int n_in,
                              void* d_out, int out_size, void* d_ws, size_t ws_size,
                              hipStream_t stream) {
    const float* X_seq  = (const float*)d_in[0];
    const float* params = (const float*)d_in[1];
    const float* W1     = (const float*)d_in[2];
    const float* b1v    = (const float*)d_in[3];
    const float* gam    = (const float*)d_in[4];
    const float* bet    = (const float*)d_in[5];
    const float* W2     = (const float*)d_in[6];
    const float* b2v    = (const float*)d_in[7];

    float* out   = (float*)d_out;
    float* score = out;          // B floats
    float* qf    = out + B_;     // B*T*D floats
    float* WS    = (float*)d_ws; // 96 floats

    hipLaunchKernelGGL(precompute_U, dim3(1), dim3(64), 0, stream, params, WS);
    hipLaunchKernelGGL(sim_kernel, dim3(NSAMP / 256), dim3(256), 0, stream, X_seq, WS, qf);
    hipLaunchKernelGGL(head_kernel, dim3(B_ / 4), dim3(256), 0, stream,
                       qf, W1, b1v, gam, bet, W2, b2v, score);
}

// Round 14
// 53.337 us; speedup vs baseline: 3.2909x; 1.5088x over previous
//
#include <hip/hip_runtime.h>
#include <math.h>

#define T_ 10
#define D_ 8
#define B_ 32768
#define NSAMP (T_ * B_)   // 327680

#define DEV static __device__ __forceinline__

// ---------------------------------------------------------------------------
// Precompute (wave-uniform math):
//   WS[0..63]  : combined layer-0 gate U0_w = RZ*RY*RX per wire (8 floats/wire)
//   WS[64..95] : per wire w, B_w = Hadamard transform of A_w = U1_w† Z U1_w,
//                divided by 4: (B00, B11, BR, BI); B[1] = BR - i*BI.
// ---------------------------------------------------------------------------
__global__ void precompute_U(const float* __restrict__ params, float* __restrict__ WS) {
    int idx = threadIdx.x;
    if (idx >= 16) return;
    float ax = 0.5f*params[idx*3+0], ay = 0.5f*params[idx*3+1], az = 0.5f*params[idx*3+2];
    float cx = cosf(ax), sx = sinf(ax);
    float cy = cosf(ay), sy = sinf(ay);
    float cz = cosf(az), sz = sinf(az);
    // M = RY*RX
    float m00r = cy*cx, m00i = sy*sx;
    float m01r = -sy*cx, m01i = -cy*sx;
    float m10r = sy*cx,  m10i = -cy*sx;
    float m11r = cy*cx,  m11i = -sy*sx;
    // U = RZ*M
    float u00r = cz*m00r + sz*m00i, u00i = cz*m00i - sz*m00r;
    float u01r = cz*m01r + sz*m01i, u01i = cz*m01i - sz*m01r;
    float u10r = cz*m10r - sz*m10i, u10i = cz*m10i + sz*m10r;
    float u11r = cz*m11r - sz*m11i, u11i = cz*m11i + sz*m11r;
    if (idx < 8) {
        float* o = WS + idx*8;
        o[0]=u00r; o[1]=u00i; o[2]=u01r; o[3]=u01i;
        o[4]=u10r; o[5]=u10i; o[6]=u11r; o[7]=u11i;
    } else {
        // A = u† Z u (Hermitian): α=A00, δ=A11 real; β=A01.
        float al = u00r*u00r+u00i*u00i - (u10r*u10r+u10i*u10i);
        float de = u01r*u01r+u01i*u01i - (u11r*u11r+u11i*u11i);
        float br = u00r*u01r+u00i*u01i - (u10r*u11r+u10i*u11i);
        float bi = u00r*u01i-u00i*u01r - (u10r*u11i-u10i*u11r);
        float* o = WS + 64 + (idx-8)*4;
        o[0] = 0.25f*(al+de+2.f*br);
        o[1] = 0.25f*(al+de-2.f*br);
        o[2] = 0.25f*(al-de);
        o[3] = -0.5f*bi;
    }
}

// d-vector of chain site: d = (d0, m1, conj(m1), d3), m1 = mr + i*mi.
DEV void dsite(const float* __restrict__ u, float th,
               float& d0, float& d3, float& mr, float& mi) {
    asm volatile("" : "+v"(th));   // pin: don't hoist all sites' sin/cos together
    float c = __cosf(th), s = __sinf(th);
    float a0r = c*c, a0i = -c*s, a1r = c*s, a1i = s*s;
    float f0r = u[0]*a0r - u[1]*a0i + u[2]*a1r - u[3]*a1i;
    float f0i = u[0]*a0i + u[1]*a0r + u[2]*a1i + u[3]*a1r;
    float f1r = u[4]*a0r - u[5]*a0i + u[6]*a1r - u[7]*a1i;
    float f1i = u[4]*a0i + u[5]*a0r + u[6]*a1i + u[7]*a1r;
    float Dpr=f0r+f1r, Dpi=f0i+f1i, Dmr=f0r-f1r, Dmi=f0i-f1i;
    d0 = Dpr*Dpr + Dpi*Dpi;
    d3 = Dmr*Dmr + Dmi*Dmi;
    mr = Dpr*Dmr + Dpi*Dmi;
    mi = Dpi*Dmr - Dpr*Dmi;
}

// ---------------------------------------------------------------------------
// One sample per LANE. MPS transfer-matrix contraction (R9/R12-proven math)
// with the chain's involution symmetry exploited (R13-proven): sigma = (1<->2),
// M[r][c] = conj(M[sigma r][sigma c]). Independent state = 16 reals.
// __launch_bounds__(256) — block-size only, NO min-waves arg: R9 evidence
// shows this yields natural allocation with zero spill (220 VGPR, 5.4 MB
// FETCH), while both (256,K) caps and NO attribute at all produced 64-84
// VGPR + 130-270 MB scratch traffic (R10-R13).
// ---------------------------------------------------------------------------
__global__ __launch_bounds__(256) void sim_kernel(const float* __restrict__ X,
                                                  const float* __restrict__ WS,
                                                  float* __restrict__ qf) {
    const int n = blockIdx.x*256 + threadIdx.x;
    const float* xp = X + n*8;
    float xr[8];
    { float4 t0 = *(const float4*)xp; float4 t1 = *(const float4*)(xp+4);
      xr[0]=0.5f*t0.x; xr[1]=0.5f*t0.y; xr[2]=0.5f*t0.z; xr[3]=0.5f*t0.w;
      xr[4]=0.5f*t1.x; xr[5]=0.5f*t1.y; xr[6]=0.5f*t1.z; xr[7]=0.5f*t1.w; }

    const float B00 = WS[64], B11 = WS[65], BR0 = WS[66], BI0 = WS[67];

    // G = closure-site (wire 0) d-vector
    float G00, G11, G01r, G01i;
    dsite(WS, xr[0], G00, G11, G01r, G01i);

    // suffix scalars: SR[wi-1] = prod_{k=wi+2..7} rho_k, ST with tau
    float SR[6], ST[6];
    SR[5]=1.f; ST[5]=1.f;
    {
        float a,b,r,i;
        dsite(WS+56, xr[7], a,b,r,i); SR[4]=0.5f*(a+b);       ST[4]=r;
        dsite(WS+48, xr[6], a,b,r,i); SR[3]=SR[4]*0.5f*(a+b); ST[3]=ST[4]*r;
        dsite(WS+40, xr[5], a,b,r,i); SR[2]=SR[3]*0.5f*(a+b); ST[2]=ST[3]*r;
        dsite(WS+32, xr[4], a,b,r,i); SR[1]=SR[2]*0.5f*(a+b); ST[1]=ST[2]*r;
        dsite(WS+24, xr[3], a,b,r,i); SR[0]=SR[1]*0.5f*(a+b); ST[0]=ST[1]*r;
    }

    // ---- init: M = diag(d_1)·circ(B_1), symmetric representation ----
    float a0,a3,a1r,a1i, c0,c3,c1r,c1i, b0r,b0i,b1r,b1i,b2r,b2i,b3r,b3i;
    {
        float D0,D3,Dmr,Dmi;
        dsite(WS+8, xr[1], D0,D3,Dmr,Dmi);
        const float C0n=WS[68], C3n=WS[69], CRn=WS[70], CIn=WS[71]; // B1 = CR - i*CI
        a0 = D0*C0n;  a3 = D0*C3n;  a1r = D0*CRn;  a1i = -D0*CIn;
        c0 = D3*C3n;  c3 = D3*C0n;  c1r = D3*CRn;  c1i =  D3*CIn;
        b0r = Dmr*CRn + Dmi*CIn;  b0i = Dmi*CRn - Dmr*CIn;   // m1*C[1]
        b1r = Dmr*C0n;            b1i = Dmi*C0n;             // m1*C[0]
        b2r = Dmr*C3n;            b2i = Dmi*C3n;             // m1*C[3]
        b3r = Dmr*CRn - Dmi*CIn;  b3i = Dmr*CIn + Dmi*CRn;   // m1*conj(C[1])
    }

    float Ev[8];

#pragma unroll
    for (int wi = 1; wi <= 6; ++wi) {
        float d0,d3,mr,mi;
        dsite(WS + 8*(wi+1), xr[wi+1], d0,d3,mr,mi);  // site wi+1: closure e + update

        // ---- closure: E_wi (uses M = sites 1..wi) ----
        {
            float Q0 = a0*G00 + c0*G11 + 2.f*(b0r*G01r - b0i*G01i);
            float Q3 = a3*G11 + c3*G00 + 2.f*(b3r*G01r + b3i*G01i);
            float Q1r = a1r*G01r - a1i*G01i + b1r*G00 + b2r*G11 + c1r*G01r + c1i*G01i;
            float Q1i = a1r*G01i + a1i*G01r + b1i*G00 - b2i*G11 + c1i*G01r - c1r*G01i;
            float P0 = a0*G11 + c0*G00 + 2.f*(b0r*G01r + b0i*G01i);
            float P3 = a3*G00 + c3*G11 + 2.f*(b3r*G01r - b3i*G01i);
            float P1r = a1r*G01r + a1i*G01i + b1r*G11 + b2r*G00 + c1r*G01r - c1i*G01i;
            float P1i = -a1r*G01i + a1i*G01r + b1i*G11 - b2i*G00 + c1i*G01r + c1r*G01i;
            float S0 = 0.5f*(B00*Q0 + B11*P0);
            float S3 = 0.5f*(B11*Q3 + B00*P3);
            float S1r = 0.5f*(BR0*Q1r + BI0*Q1i + BR0*P1r - BI0*P1i);
            float S1i = 0.5f*(BR0*Q1i - BI0*Q1r + BR0*P1i + BI0*P1r);
            float eR = SR[wi-1], eT = ST[wi-1];
            float e1r = mr*eT, e1i = mi*eT;
            Ev[wi] = eR*(d0*S0 + d3*S3) + 2.f*(e1r*S1r - e1i*S1i);
        }

        // ---- update: M <- M · diag(d_{wi+1}) · circ(B_{wi+1}) ----
        {
            const float* Bp = WS + 64 + 4*(wi+1);
            const float C0n=Bp[0], C3n=Bp[1], CRn=Bp[2], CIn=Bp[3]; // C1 = CR - i*CI
            // row 0
            float n0 = a0*d0, n3 = a3*d3;
            float n1r = a1r*mr - a1i*mi, n1i = a1r*mi + a1i*mr;
            a0  = n0*C0n + n3*C3n + 2.f*(n1r*CRn + n1i*CIn);
            a3  = n0*C3n + n3*C0n + 2.f*(n1r*CRn - n1i*CIn);
            a1r = (n0+n3)*CRn + n1r*(C0n+C3n);
            a1i = (n3-n0)*CIn + n1i*(C0n-C3n);
            // row 3
            float p0 = c0*d0, p3 = c3*d3;
            float p1r = c1r*mr - c1i*mi, p1i = c1r*mi + c1i*mr;
            c0  = p0*C0n + p3*C3n + 2.f*(p1r*CRn + p1i*CIn);
            c3  = p0*C3n + p3*C0n + 2.f*(p1r*CRn - p1i*CIn);
            c1r = (p0+p3)*CRn + p1r*(C0n+C3n);
            c1i = (p3-p0)*CIn + p1i*(C0n-C3n);
            // row 1
            float q0r = b0r*d0, q0i = b0i*d0;
            float q1r = b1r*mr - b1i*mi, q1i = b1r*mi + b1i*mr;
            float q2r = b2r*mr + b2i*mi, q2i = b2i*mr - b2r*mi;
            float q3r = b3r*d3, q3i = b3i*d3;
            float nb0r = q0r*C0n + q1r*CRn + q1i*CIn + q2r*CRn - q2i*CIn + q3r*C3n;
            float nb0i = q0i*C0n + q1i*CRn - q1r*CIn + q2i*CRn + q2r*CIn + q3i*C3n;
            float nb1r = q0r*CRn + q0i*CIn + q1r*C0n + q2r*C3n + q3r*CRn - q3i*CIn;
            float nb1i = q0i*CRn - q0r*CIn + q1i*C0n + q2i*C3n + q3i*CRn + q3r*CIn;
            float nb2r = q0r*CRn - q0i*CIn + q1r*C3n + q2r*C0n + q3r*CRn + q3i*CIn;
            float nb2i = q0i*CRn + q0r*CIn + q1i*C3n + q2i*C0n + q3i*CRn - q3r*CIn;
            float nb3r = q0r*C3n + q1r*CRn - q1i*CIn + q2r*CRn + q2i*CIn + q3r*C0n;
            float nb3i = q0i*C3n + q1i*CRn + q1r*CIn + q2i*CRn - q2r*CIn + q3i*C0n;
            b0r=nb0r; b0i=nb0i; b1r=nb1r; b1i=nb1i;
            b2r=nb2r; b2i=nb2i; b3r=nb3r; b3i=nb3i;
        }
    }

    // ---- final closures from M = sites 1..7 ----
    {
        float Q0 = a0*G00 + c0*G11 + 2.f*(b0r*G01r - b0i*G01i);
        float Q3 = a3*G11 + c3*G00 + 2.f*(b3r*G01r + b3i*G01i);
        float Q1r = a1r*G01r - a1i*G01i + b1r*G00 + b2r*G11 + c1r*G01r + c1i*G01i;
        float Q1i = a1r*G01i + a1i*G01r + b1i*G00 - b2i*G11 + c1i*G01r - c1r*G01i;
        Ev[7] = B00*Q0 + B11*Q3 + 2.f*(BR0*Q1r + BI0*Q1i);
        Ev[0] = 0.5f*(Q0 + Q3);
    }

    const int t_ = n >> 15;          // n / B
    const int b_ = n & (B_-1);       // n % B
    float* o = qf + b_*(T_*D_) + t_*D_;
    float4 o0 = {Ev[0], Ev[1], Ev[2], Ev[3]};
    float4 o1 = {Ev[4], Ev[5], Ev[6], Ev[7]};
    *(float4*)o = o0;
    *(float4*)(o+4) = o1;
}

// One wave64 per batch row: h = qf_row @ W1 + b1 ; LayerNorm ; ReLU ; sigmoid(h @ W2 + b2)
__global__ __launch_bounds__(256) void head_kernel(const float* __restrict__ qf,
                                                   const float* __restrict__ W1,
                                                   const float* __restrict__ b1v,
                                                   const float* __restrict__ gam,
                                                   const float* __restrict__ bet,
                                                   const float* __restrict__ W2,
                                                   const float* __restrict__ b2v,
                                                   float* __restrict__ score) {
    const int lane = threadIdx.x & 63;
    int b = (blockIdx.x << 2) + (threadIdx.x >> 6);
    b = __builtin_amdgcn_readfirstlane(b);
    const float* row = qf + b * (T_ * D_);
    float h = b1v[lane];
#pragma unroll
    for (int k = 0; k < T_ * D_; ++k)
        h = fmaf(row[k], W1[(k << 6) + lane], h);
    float t = h;
#pragma unroll
    for (int m = 1; m < 64; m <<= 1) t += __shfl_xor(t, m, 64);
    float mu = t * (1.0f / 64.0f);
    float d = h - mu;
    float vv = d * d;
#pragma unroll
    for (int m = 1; m < 64; m <<= 1) vv += __shfl_xor(vv, m, 64);
    float rs = rsqrtf(vv * (1.0f / 64.0f) + 1e-5f);
    float hn = fmaxf(d * rs * gam[lane] + bet[lane], 0.f);
    float sacc = hn * W2[lane];
#pragma unroll
    for (int m = 1; m < 64; m <<= 1) sacc += __shfl_xor(sacc, m, 64);
    if (lane == 0) score[b] = 1.0f / (1.0f + expf(-(sacc + b2v[0])));
}

extern "C" void kernel_launch(void* const* d_in, const int* in_sizes, int n_in,
                              void* d_out, int out_size, void* d_ws, size_t ws_size,
                              hipStream_t stream) {
    const float* X_seq  = (const float*)d_in[0];
    const float* params = (const float*)d_in[1];
    const float* W1     = (const float*)d_in[2];
    const float* b1v    = (const float*)d_in[3];
    const float* gam    = (const float*)d_in[4];
    const float* bet    = (const float*)d_in[5];
    const float* W2     = (const float*)d_in[6];
    const float* b2v    = (const float*)d_in[7];

    float* out   = (float*)d_out;
    float* score = out;          // B floats
    float* qf    = out + B_;     // B*T*D floats
    float* WS    = (float*)d_ws; // 96 floats

    hipLaunchKernelGGL(precompute_U, dim3(1), dim3(64), 0, stream, params, WS);
    hipLaunchKernelGGL(sim_kernel, dim3(NSAMP / 256), dim3(256), 0, stream, X_seq, WS, qf);
    hipLaunchKernelGGL(head_kernel, dim3(B_ / 4), dim3(256), 0, stream,
                       qf, W1, b1v, gam, bet, W2, b2v, score);
}